// Round 1
// baseline (482.671 us; speedup 1.0000x reference)
//
#include <hip/hip_runtime.h>

typedef short s8v __attribute__((ext_vector_type(8)));
typedef short s4v __attribute__((ext_vector_type(4)));
typedef float f4v __attribute__((ext_vector_type(4)));

#define DEV __device__ __forceinline__

DEV short f2bs(float f){
  unsigned int u = __float_as_uint(f);
  u += 0x7fffu + ((u >> 16) & 1u);
  return (short)(u >> 16);
}
DEV float b2f(short s){
  return __uint_as_float(((unsigned int)(unsigned short)s) << 16);
}
DEV float lrelu(float x){ return x >= 0.f ? x : 0.01f*x; }

// ---------------- K0: weight prep ----------------
// wreg byte layout:
//   0      w1T  f32  [27][32]          (3456 B)
//   3456   w2b  bf16 [9][64][32]       (36864 B)   [kk][cout][cin]
//   40320  w3b  bf16 [9][64][64]       (73728 B)
//   114048 rw2b bf16 [64][64] row-major
//   122240 wqb / 130432 wkb / 138624 wvb / 146816 wob
__global__ __launch_bounds__(256) void k0_prep(
    const float* __restrict__ w1, const float* __restrict__ w2,
    const float* __restrict__ w3, const float* __restrict__ rw2,
    const float* __restrict__ wq, const float* __restrict__ wk,
    const float* __restrict__ wv, const float* __restrict__ wo,
    char* __restrict__ wreg)
{
  int idx = blockIdx.x*256 + threadIdx.x;
  float* w1T = (float*)(wreg);
  short* w2b = (short*)(wreg + 3456);
  short* w3b = (short*)(wreg + 40320);
  short* rw2b = (short*)(wreg + 114048);
  short* wqb  = (short*)(wreg + 122240);
  short* wkb  = (short*)(wreg + 130432);
  short* wvb  = (short*)(wreg + 138624);
  short* wob  = (short*)(wreg + 146816);
  if (idx < 864){
    int k = idx >> 5, c = idx & 31;
    w1T[idx] = w1[c*27 + k];
  } else if (idx < 19296){
    int j = idx - 864;
    int kk = j / 2048, c = (j >> 5) & 63, ci = j & 31;
    w2b[j] = f2bs(w2[c*288 + ci*9 + kk]);
  } else if (idx < 56160){
    int j = idx - 19296;
    int kk = j / 4096, c = (j >> 6) & 63, ci = j & 63;
    w3b[j] = f2bs(w3[c*576 + ci*9 + kk]);
  } else if (idx < 60256){
    int j = idx - 56160; rw2b[j] = f2bs(rw2[j]);
  } else if (idx < 64352){
    int j = idx - 60256; wqb[j] = f2bs(wq[j]);
  } else if (idx < 68448){
    int j = idx - 64352; wkb[j] = f2bs(wk[j]);
  } else if (idx < 72544){
    int j = idx - 68448; wvb[j] = f2bs(wv[j]);
  } else if (idx < 76640){
    int j = idx - 72544; wob[j] = f2bs(wo[j]);
  }
}

// ---------------- K1: conv1 3->32, stride1, border pad (VALU fp32) ----------------
// dst: per-launch-compact [v][512][512][32] bf16 (channel-last)
__global__ __launch_bounds__(256) void k1_conv1(
    const float* __restrict__ vt, short* __restrict__ dst,
    const float* __restrict__ w1T, const float* __restrict__ b1, int v0)
{
  int lane = threadIdx.x & 63, ty = threadIdx.x >> 6;
  int x = blockIdx.x*64 + lane;
  int y = blockIdx.y*4 + ty;
  const float* src = vt + (size_t)(v0 + blockIdx.z)*3*512*512;
  float xin[27];
  #pragma unroll
  for (int ci=0; ci<3; ci++){
    #pragma unroll
    for (int ky=0; ky<3; ky++){
      int iy = min(max(y+ky-1, 0), 511);
      #pragma unroll
      for (int kx=0; kx<3; kx++){
        int ix = min(max(x+kx-1, 0), 511);
        xin[(ci*3+ky)*3+kx] = src[(ci*512 + iy)*512 + ix];
      }
    }
  }
  float acc[32];
  #pragma unroll
  for (int c=0;c<32;c++) acc[c] = b1[c];
  #pragma unroll
  for (int k=0;k<27;k++){
    const float* wr = w1T + k*32;
    #pragma unroll
    for (int c=0;c<32;c++) acc[c] += wr[c]*xin[k];
  }
  s8v pk[4];
  #pragma unroll
  for (int c=0;c<32;c++) pk[c>>3][c&7] = f2bs(lrelu(acc[c]));
  short* o = dst + ((size_t)blockIdx.z*512*512 + (size_t)y*512 + x)*32;
  #pragma unroll
  for (int q=0;q<4;q++) *(s8v*)(o + q*8) = pk[q];
}

// ---------------- conv2/conv3: implicit-GEMM MFMA, stride 2 ----------------
// src: [v][IH][IW][CIN] bf16 ch-last ; dst: [dstV0+v][OH][OW][64] bf16 ch-last
// wave = 16 output pixels (one row segment); M=64 cout, K = 9*CIN
template<int CIN>
__global__ __launch_bounds__(256) void conv_mfma(
    const short* __restrict__ src0, short* __restrict__ dst,
    const short* __restrict__ wb, const float* __restrict__ bias,
    int IH, int IW, int OW, int dstV0)
{
  const int l = threadIdx.x & 63, w = threadIdx.x >> 6;
  const int p = l & 15, g = l >> 4;
  const int ox = blockIdx.x*64 + w*16 + p;
  const int oy = blockIdx.y;
  const short* src = src0 + (size_t)blockIdx.z*IH*IW*CIN;
  const f4v FZ = {0.f,0.f,0.f,0.f};
  f4v acc[4] = {FZ,FZ,FZ,FZ};
  #pragma unroll
  for (int ky=0;ky<3;ky++){
    int iy = min(max(2*oy+ky-1, 0), IH-1);
    #pragma unroll
    for (int kx=0;kx<3;kx++){
      int ix = min(max(2*ox+kx-1, 0), IW-1);
      const short* bp = src + ((size_t)iy*IW + ix)*CIN + g*8;
      #pragma unroll
      for (int ch=0; ch<CIN/32; ch++){
        s8v bfrag = *(const s8v*)(bp + ch*32);
        #pragma unroll
        for (int m=0;m<4;m++){
          s8v afrag = *(const s8v*)(wb + ((ky*3+kx)*64 + m*16 + p)*CIN + ch*32 + g*8);
          acc[m] = __builtin_amdgcn_mfma_f32_16x16x32_bf16(afrag, bfrag, acc[m], 0,0,0);
        }
      }
    }
  }
  const int OH = gridDim.y;
  short* o = dst + (((size_t)(dstV0 + blockIdx.z)*OH + oy)*OW + ox)*64;
  #pragma unroll
  for (int m=0;m<4;m++){
    f4v bb = *(const f4v*)(bias + m*16 + g*4);
    s4v pk;
    #pragma unroll
    for (int r=0;r<4;r++) pk[r] = f2bs(lrelu(acc[m][r] + bb[r]));
    *(s4v*)(o + m*16 + g*4) = pk;
  }
}

// ---------------- K4: bilinear gather ----------------
// nts: [8][128][128][64] bf16 ch-last. wave = 64 tokens (serial), lane = feature.
__global__ __launch_bounds__(256) void k4_gather(
    const short* __restrict__ nts, const float* __restrict__ uvi,
    float* __restrict__ outFeats, short* __restrict__ featsb)
{
  int lane = threadIdx.x & 63, w = threadIdx.x >> 6;
  int tk0 = blockIdx.x*256 + w*64;
  int myTk = tk0 + lane;
  float u0 = uvi[(size_t)myTk*3+0];
  float v0 = uvi[(size_t)myTk*3+1];
  float f0 = uvi[(size_t)myTk*3+2];
  for (int i=0;i<64;i++){
    float ui = __shfl(u0, i, 64);
    float vi = __shfl(v0, i, 64);
    int vid = (int)__shfl(f0, i, 64);
    float xf = ui*127.f, yf = vi*127.f;
    int x0 = min(max((int)floorf(xf), 0), 126);
    int y0 = min(max((int)floorf(yf), 0), 126);
    float wx = xf - (float)x0, wy = yf - (float)y0;
    const short* b = nts + ((size_t)((vid*128 + y0)*128 + x0))*64 + lane;
    float f00 = b2f(b[0]),    f01 = b2f(b[64]);
    float f10 = b2f(b[8192]), f11 = b2f(b[8192+64]);
    float val = (f00*(1.f-wx) + f01*wx)*(1.f-wy) + (f10*(1.f-wx) + f11*wx)*wy;
    int tk = tk0 + i;
    outFeats[(size_t)tk*64 + lane] = val;
    if (featsb) featsb[(size_t)tk*64 + lane] = f2bs(val);
  }
}

// ---------------- K5: rayMLP + MHA, MFMA batched over 16 points/wave ----------------
// lane: p = l&15 (point in wave tile), g = l>>4.
// D-frag: row j = m*16+g*4+r, col = p.  B-frag: col = p, k = kc*32+g*8+e.
#define AFRG(W) (*(const s8v*)((W) + (m*16 + p)*64 + kc*32 + g*8))

template<bool FB16>
__global__ __launch_bounds__(256) void k5_attn(
    const short* __restrict__ featsb, const float* __restrict__ featsF,
    const float* __restrict__ raydir,
    const float* __restrict__ rw1, const float* __restrict__ rb1,
    const short* __restrict__ rw2b, const float* __restrict__ rb2,
    const short* __restrict__ wqb, const float* __restrict__ bq,
    const short* __restrict__ wkb, const float* __restrict__ bk,
    const short* __restrict__ wvb, const float* __restrict__ bv,
    const short* __restrict__ wob, const float* __restrict__ bo,
    float* __restrict__ outFused)
{
  __shared__ uint4 ldsq[576];                 // 4 waves * 16 pts * 72 bf16 (pad 64->72)
  unsigned int* ldsu = (unsigned int*)ldsq;
  const int l = threadIdx.x & 63, wid = threadIdx.x >> 6;
  const int p = l & 15, g = l >> 4;
  const int pt = blockIdx.x*64 + wid*16 + p;
  const f4v FZ = {0.f,0.f,0.f,0.f};

  // D-frag (float H[4][4]) -> LDS [p][j] bf16 -> B-frags OB[0..1]
#define RELAYOUT(H, OB) { \
    _Pragma("unroll") \
    for (int m_=0;m_<4;m_++){ \
      unsigned int lo_ = (unsigned int)(unsigned short)f2bs(H[m_][0]) \
                       | ((unsigned int)(unsigned short)f2bs(H[m_][1])<<16); \
      unsigned int hi_ = (unsigned int)(unsigned short)f2bs(H[m_][2]) \
                       | ((unsigned int)(unsigned short)f2bs(H[m_][3])<<16); \
      int di_ = wid*576 + p*36 + m_*8 + g*2; \
      ldsu[di_] = lo_; ldsu[di_+1] = hi_; \
    } \
    OB[0] = __builtin_bit_cast(s8v, ldsq[wid*144 + p*9 + g]); \
    OB[1] = __builtin_bit_cast(s8v, ldsq[wid*144 + p*9 + 4 + g]); \
  }

  // ---- ray MLP hidden: relu(rw1 @ rd + rb1), computed directly in D-frag layout ----
  float rd0 = raydir[(size_t)pt*3+0];
  float rd1 = raydir[(size_t)pt*3+1];
  float rd2 = raydir[(size_t)pt*3+2];
  float h[4][4];
  #pragma unroll
  for (int m=0;m<4;m++){
    #pragma unroll
    for (int r=0;r<4;r++){
      int j = m*16 + g*4 + r;
      h[m][r] = fmaxf(rb1[j] + rw1[j*3]*rd0 + rw1[j*3+1]*rd1 + rw1[j*3+2]*rd2, 0.f);
    }
  }
  s8v xb[2];
  RELAYOUT(h, xb);

  // ---- rf = rw2 @ h + rb2 ----
  f4v acc[4];
  #pragma unroll
  for (int m=0;m<4;m++) acc[m] = FZ;
  #pragma unroll
  for (int kc=0;kc<2;kc++){
    #pragma unroll
    for (int m=0;m<4;m++)
      acc[m] = __builtin_amdgcn_mfma_f32_16x16x32_bf16(AFRG(rw2b), xb[kc], acc[m], 0,0,0);
  }
  float rf[4][4];
  #pragma unroll
  for (int m=0;m<4;m++){
    f4v bb = *(const f4v*)(rb2 + m*16 + g*4);
    #pragma unroll
    for (int r=0;r<4;r++) rf[m][r] = acc[m][r] + bb[r];
  }
  RELAYOUT(rf, xb);

  // ---- qh = wq @ rf + bq ----
  #pragma unroll
  for (int m=0;m<4;m++) acc[m] = FZ;
  #pragma unroll
  for (int kc=0;kc<2;kc++){
    #pragma unroll
    for (int m=0;m<4;m++)
      acc[m] = __builtin_amdgcn_mfma_f32_16x16x32_bf16(AFRG(wqb), xb[kc], acc[m], 0,0,0);
  }
  float qh[4][4];
  #pragma unroll
  for (int m=0;m<4;m++){
    f4v bb = *(const f4v*)(bq + m*16 + g*4);
    #pragma unroll
    for (int r=0;r<4;r++) qh[m][r] = acc[m][r] + bb[r];
  }

  // ---- per-token K/V projections, scores ----
  float sc[3][4];
  float vh[3][4][4];
  #pragma unroll
  for (int t=0;t<3;t++){
    s8v fb[2];
    if constexpr (FB16){
      const short* fp = featsb + (size_t)(pt*3+t)*64;
      fb[0] = *(const s8v*)(fp + g*8);
      fb[1] = *(const s8v*)(fp + 32 + g*8);
    } else {
      const float* fp = featsF + (size_t)(pt*3+t)*64;
      #pragma unroll
      for (int kc=0;kc<2;kc++){
        f4v a0 = *(const f4v*)(fp + kc*32 + g*8);
        f4v a1 = *(const f4v*)(fp + kc*32 + g*8 + 4);
        s8v tmp;
        #pragma unroll
        for (int e=0;e<4;e++){ tmp[e] = f2bs(a0[e]); tmp[e+4] = f2bs(a1[e]); }
        fb[kc] = tmp;
      }
    }
    f4v ka[4];
    #pragma unroll
    for (int m=0;m<4;m++) ka[m] = FZ;
    #pragma unroll
    for (int kc=0;kc<2;kc++){
      #pragma unroll
      for (int m=0;m<4;m++)
        ka[m] = __builtin_amdgcn_mfma_f32_16x16x32_bf16(AFRG(wkb), fb[kc], ka[m], 0,0,0);
    }
    #pragma unroll
    for (int m=0;m<4;m++){
      f4v bb = *(const f4v*)(bk + m*16 + g*4);
      float part = 0.f;
      #pragma unroll
      for (int r=0;r<4;r++) part += qh[m][r]*(ka[m][r] + bb[r]);
      part += __shfl_xor(part, 16, 64);
      part += __shfl_xor(part, 32, 64);
      sc[t][m] = part*0.25f;                  // / sqrt(16)
    }
    f4v va[4];
    #pragma unroll
    for (int m=0;m<4;m++) va[m] = FZ;
    #pragma unroll
    for (int kc=0;kc<2;kc++){
      #pragma unroll
      for (int m=0;m<4;m++)
        va[m] = __builtin_amdgcn_mfma_f32_16x16x32_bf16(AFRG(wvb), fb[kc], va[m], 0,0,0);
    }
    #pragma unroll
    for (int m=0;m<4;m++){
      f4v bb = *(const f4v*)(bv + m*16 + g*4);
      #pragma unroll
      for (int r=0;r<4;r++) vh[t][m][r] = va[m][r] + bb[r];
    }
  }

  // ---- softmax over 3 tokens (per head m, per lane) + PV ----
  float o[4][4];
  #pragma unroll
  for (int m=0;m<4;m++){
    float mx = fmaxf(fmaxf(sc[0][m], sc[1][m]), sc[2][m]);
    float e0 = __expf(sc[0][m]-mx);
    float e1 = __expf(sc[1][m]-mx);
    float e2 = __expf(sc[2][m]-mx);
    float inv = 1.f/(e0+e1+e2);
    e0 *= inv; e1 *= inv; e2 *= inv;
    #pragma unroll
    for (int r=0;r<4;r++)
      o[m][r] = e0*vh[0][m][r] + e1*vh[1][m][r] + e2*vh[2][m][r];
  }
  RELAYOUT(o, xb);

  // ---- out = wo @ o + bo ----
  #pragma unroll
  for (int m=0;m<4;m++) acc[m] = FZ;
  #pragma unroll
  for (int kc=0;kc<2;kc++){
    #pragma unroll
    for (int m=0;m<4;m++)
      acc[m] = __builtin_amdgcn_mfma_f32_16x16x32_bf16(AFRG(wob), xb[kc], acc[m], 0,0,0);
  }
  #pragma unroll
  for (int m=0;m<4;m++){
    f4v bb = *(const f4v*)(bo + m*16 + g*4);
    f4v res;
    #pragma unroll
    for (int r=0;r<4;r++) res[r] = acc[m][r] + bb[r];
    *(f4v*)(outFused + (size_t)pt*64 + m*16 + g*4) = res;
  }
#undef RELAYOUT
}

extern "C" void kernel_launch(void* const* d_in, const int* in_sizes, int n_in,
                              void* d_out, int out_size, void* d_ws, size_t ws_size,
                              hipStream_t stream)
{
  const float* view_tex = (const float*)d_in[0];
  const float* uvi    = (const float*)d_in[1];
  const float* raydir = (const float*)d_in[2];
  const float* w1 = (const float*)d_in[3];
  const float* b1 = (const float*)d_in[4];
  const float* w2 = (const float*)d_in[5];
  const float* b2 = (const float*)d_in[6];
  const float* w3 = (const float*)d_in[7];
  const float* b3 = (const float*)d_in[8];
  const float* rw1 = (const float*)d_in[9];
  const float* rb1 = (const float*)d_in[10];
  const float* rw2 = (const float*)d_in[11];
  const float* rb2 = (const float*)d_in[12];
  const float* wq = (const float*)d_in[13];
  const float* bq = (const float*)d_in[14];
  const float* wk = (const float*)d_in[15];
  const float* bk = (const float*)d_in[16];
  const float* wv = (const float*)d_in[17];
  const float* bv = (const float*)d_in[18];
  const float* wo = (const float*)d_in[19];
  const float* bo = (const float*)d_in[20];
  float* out = (float*)d_out;

  const int V = in_sizes[0] / (3*512*512);     // 8
  const int B = in_sizes[1] / 9;               // 262144
  const size_t FEATS_OFF = (size_t)B*64;

  const size_t C1F  = (size_t)V*512*512*32*2;
  const size_t C2F  = (size_t)V*256*256*64*2;
  const size_t C1V  = (size_t)512*512*32*2;
  const size_t C2V  = (size_t)256*256*64*2;
  const size_t NTSB = (size_t)V*128*128*64*2;
  const size_t WREG = 262144;
  const size_t FEATB = (size_t)B*3*64*2;

  char* base = (char*)d_ws;
  bool full = (ws_size >= C1F + C2F + NTSB + WREG) && (C1F >= FEATB);

  char *c1, *c2, *ntsp, *wreg;
  short* featsb = nullptr;
  if (full){
    c1 = base; c2 = c1 + C1F; ntsp = c2 + C2F; wreg = ntsp + NTSB;
    featsb = (short*)base;    // reuses conv1 buffer (dead after conv2)
  } else {
    c1 = base; c2 = c1 + C1V; ntsp = c2 + C2V; wreg = ntsp + NTSB;
  }
  float* w1T = (float*)(wreg);
  short* w2b = (short*)(wreg + 3456);
  short* w3b = (short*)(wreg + 40320);
  short* rw2b = (short*)(wreg + 114048);
  short* wqb  = (short*)(wreg + 122240);
  short* wkb  = (short*)(wreg + 130432);
  short* wvb  = (short*)(wreg + 138624);
  short* wob  = (short*)(wreg + 146816);

  k0_prep<<<dim3(300),256,0,stream>>>(w1,w2,w3,rw2,wq,wk,wv,wo,wreg);

  if (full){
    k1_conv1<<<dim3(8,128,V),256,0,stream>>>(view_tex,(short*)c1,w1T,b1,0);
    conv_mfma<32><<<dim3(4,256,V),256,0,stream>>>((const short*)c1,(short*)c2,w2b,b2,512,512,256,0);
    conv_mfma<64><<<dim3(2,128,V),256,0,stream>>>((const short*)c2,(short*)ntsp,w3b,b3,256,256,128,0);
  } else {
    for (int v=0; v<V; v++){
      k1_conv1<<<dim3(8,128,1),256,0,stream>>>(view_tex,(short*)c1,w1T,b1,v);
      conv_mfma<32><<<dim3(4,256,1),256,0,stream>>>((const short*)c1,(short*)c2,w2b,b2,512,512,256,0);
      conv_mfma<64><<<dim3(2,128,1),256,0,stream>>>((const short*)c2,(short*)ntsp,w3b,b3,256,256,128,v);
    }
  }

  k4_gather<<<dim3((B*3)/256),256,0,stream>>>((const short*)ntsp, uvi, out + FEATS_OFF, featsb);

  if (full)
    k5_attn<true><<<dim3(B/64),256,0,stream>>>(featsb, nullptr, raydir, rw1, rb1,
        rw2b, rb2, wqb, bq, wkb, bk, wvb, bv, wob, bo, out);
  else
    k5_attn<false><<<dim3(B/64),256,0,stream>>>(nullptr, out + FEATS_OFF, raydir, rw1, rb1,
        rw2b, rb2, wqb, bq, wkb, bk, wvb, bv, wob, bo, out);
}

// Round 2
// 426.538 us; speedup vs baseline: 1.1316x; 1.1316x over previous
//
#include <hip/hip_runtime.h>

typedef short s8v __attribute__((ext_vector_type(8)));
typedef short s4v __attribute__((ext_vector_type(4)));
typedef float f4v __attribute__((ext_vector_type(4)));

#define DEV __device__ __forceinline__

DEV short f2bs(float f){
  unsigned int u = __float_as_uint(f);
  u += 0x7fffu + ((u >> 16) & 1u);
  return (short)(u >> 16);
}
DEV float b2f(short s){
  return __uint_as_float(((unsigned int)(unsigned short)s) << 16);
}
DEV float lrelu(float x){ return x >= 0.f ? x : 0.01f*x; }

// ---------------- K0: weight prep ----------------
__global__ __launch_bounds__(256) void k0_prep(
    const float* __restrict__ w1, const float* __restrict__ w2,
    const float* __restrict__ w3, const float* __restrict__ rw2,
    const float* __restrict__ wq, const float* __restrict__ wk,
    const float* __restrict__ wv, const float* __restrict__ wo,
    char* __restrict__ wreg)
{
  int idx = blockIdx.x*256 + threadIdx.x;
  float* w1T = (float*)(wreg);
  short* w2b = (short*)(wreg + 3456);
  short* w3b = (short*)(wreg + 40320);
  short* rw2b = (short*)(wreg + 114048);
  short* wqb  = (short*)(wreg + 122240);
  short* wkb  = (short*)(wreg + 130432);
  short* wvb  = (short*)(wreg + 138624);
  short* wob  = (short*)(wreg + 146816);
  if (idx < 864){
    int k = idx >> 5, c = idx & 31;
    w1T[idx] = w1[c*27 + k];
  } else if (idx < 19296){
    int j = idx - 864;
    int kk = j / 2048, c = (j >> 5) & 63, ci = j & 31;
    w2b[j] = f2bs(w2[c*288 + ci*9 + kk]);
  } else if (idx < 56160){
    int j = idx - 19296;
    int kk = j / 4096, c = (j >> 6) & 63, ci = j & 63;
    w3b[j] = f2bs(w3[c*576 + ci*9 + kk]);
  } else if (idx < 60256){
    int j = idx - 56160; rw2b[j] = f2bs(rw2[j]);
  } else if (idx < 64352){
    int j = idx - 60256; wqb[j] = f2bs(wq[j]);
  } else if (idx < 68448){
    int j = idx - 64352; wkb[j] = f2bs(wk[j]);
  } else if (idx < 72544){
    int j = idx - 68448; wvb[j] = f2bs(wv[j]);
  } else if (idx < 76640){
    int j = idx - 72544; wob[j] = f2bs(wo[j]);
  }
}

// ---------------- K1: conv1 3->32, stride1, border pad (VALU fp32) ----------------
__global__ __launch_bounds__(256) void k1_conv1(
    const float* __restrict__ vt, short* __restrict__ dst,
    const float* __restrict__ w1T, const float* __restrict__ b1, int v0)
{
  int lane = threadIdx.x & 63, ty = threadIdx.x >> 6;
  int x = blockIdx.x*64 + lane;
  int y = blockIdx.y*4 + ty;
  const float* src = vt + (size_t)(v0 + blockIdx.z)*3*512*512;
  float xin[27];
  #pragma unroll
  for (int ci=0; ci<3; ci++){
    #pragma unroll
    for (int ky=0; ky<3; ky++){
      int iy = min(max(y+ky-1, 0), 511);
      #pragma unroll
      for (int kx=0; kx<3; kx++){
        int ix = min(max(x+kx-1, 0), 511);
        xin[(ci*3+ky)*3+kx] = src[(ci*512 + iy)*512 + ix];
      }
    }
  }
  float acc[32];
  #pragma unroll
  for (int c=0;c<32;c++) acc[c] = b1[c];
  #pragma unroll
  for (int k=0;k<27;k++){
    const float* wr = w1T + k*32;
    #pragma unroll
    for (int c=0;c<32;c++) acc[c] += wr[c]*xin[k];
  }
  s8v pk[4];
  #pragma unroll
  for (int c=0;c<32;c++) pk[c>>3][c&7] = f2bs(lrelu(acc[c]));
  short* o = dst + ((size_t)blockIdx.z*512*512 + (size_t)y*512 + x)*32;
  #pragma unroll
  for (int q=0;q<4;q++) *(s8v*)(o + q*8) = pk[q];
}

// ---------------- conv2/conv3: implicit-GEMM MFMA, stride 2 ----------------
template<int CIN>
__global__ __launch_bounds__(256) void conv_mfma(
    const short* __restrict__ src0, short* __restrict__ dst,
    const short* __restrict__ wb, const float* __restrict__ bias,
    int IH, int IW, int OW, int dstV0)
{
  const int l = threadIdx.x & 63, w = threadIdx.x >> 6;
  const int p = l & 15, g = l >> 4;
  const int ox = blockIdx.x*64 + w*16 + p;
  const int oy = blockIdx.y;
  const short* src = src0 + (size_t)blockIdx.z*IH*IW*CIN;
  const f4v FZ = {0.f,0.f,0.f,0.f};
  f4v acc[4] = {FZ,FZ,FZ,FZ};
  #pragma unroll
  for (int ky=0;ky<3;ky++){
    int iy = min(max(2*oy+ky-1, 0), IH-1);
    #pragma unroll
    for (int kx=0;kx<3;kx++){
      int ix = min(max(2*ox+kx-1, 0), IW-1);
      const short* bp = src + ((size_t)iy*IW + ix)*CIN + g*8;
      #pragma unroll
      for (int ch=0; ch<CIN/32; ch++){
        s8v bfrag = *(const s8v*)(bp + ch*32);
        #pragma unroll
        for (int m=0;m<4;m++){
          s8v afrag = *(const s8v*)(wb + ((ky*3+kx)*64 + m*16 + p)*CIN + ch*32 + g*8);
          acc[m] = __builtin_amdgcn_mfma_f32_16x16x32_bf16(afrag, bfrag, acc[m], 0,0,0);
        }
      }
    }
  }
  const int OH = gridDim.y;
  short* o = dst + (((size_t)(dstV0 + blockIdx.z)*OH + oy)*OW + ox)*64;
  #pragma unroll
  for (int m=0;m<4;m++){
    f4v bb = *(const f4v*)(bias + m*16 + g*4);
    s4v pk;
    #pragma unroll
    for (int r=0;r<4;r++) pk[r] = f2bs(lrelu(acc[m][r] + bb[r]));
    *(s4v*)(o + m*16 + g*4) = pk;
  }
}

// ---------------- K5: fused gather + rayMLP + MHA ----------------
// wave = 16 points; lane (p = l&15: point, g = l>>4: 8-ch chunk of B-frag).
// Gather: lane (p,g) directly loads its own B-frag channels (kc*32+g*8..+8)
// for the 4 bilinear corners (4 g-lanes x 2 kc cover 64 ch exactly once).
#define AFRG(W) (*(const s8v*)((W) + (m*16 + p)*64 + kc*32 + g*8))

__global__ __launch_bounds__(256) void k5_fused(
    const short* __restrict__ nts, const float* __restrict__ uvi,
    const float* __restrict__ raydir,
    const float* __restrict__ rw1, const float* __restrict__ rb1,
    const short* __restrict__ rw2b, const float* __restrict__ rb2,
    const short* __restrict__ wqb, const float* __restrict__ bq,
    const short* __restrict__ wkb, const float* __restrict__ bk,
    const short* __restrict__ wvb, const float* __restrict__ bv,
    const short* __restrict__ wob, const float* __restrict__ bo,
    float* __restrict__ outFused, float* __restrict__ outFeats)
{
  __shared__ uint4 ldsq[576];                 // 4 waves * 16 pts * 72 bf16 (pad 64->72)
  unsigned int* ldsu = (unsigned int*)ldsq;
  const int l = threadIdx.x & 63, wid = threadIdx.x >> 6;
  const int p = l & 15, g = l >> 4;
  const int pt = blockIdx.x*64 + wid*16 + p;
  const f4v FZ = {0.f,0.f,0.f,0.f};

#define RELAYOUT(H, OB) { \
    _Pragma("unroll") \
    for (int m_=0;m_<4;m_++){ \
      unsigned int lo_ = (unsigned int)(unsigned short)f2bs(H[m_][0]) \
                       | ((unsigned int)(unsigned short)f2bs(H[m_][1])<<16); \
      unsigned int hi_ = (unsigned int)(unsigned short)f2bs(H[m_][2]) \
                       | ((unsigned int)(unsigned short)f2bs(H[m_][3])<<16); \
      int di_ = wid*576 + p*36 + m_*8 + g*2; \
      ldsu[di_] = lo_; ldsu[di_+1] = hi_; \
    } \
    OB[0] = __builtin_bit_cast(s8v, ldsq[wid*144 + p*9 + g]); \
    OB[1] = __builtin_bit_cast(s8v, ldsq[wid*144 + p*9 + 4 + g]); \
  }

  // ---- gather: 3 tokens, each lane its own 2x8-ch fragment chunks ----
  s8v fb[3][2];
  const float* up = uvi + (size_t)pt*9;
  #pragma unroll
  for (int t=0;t<3;t++){
    float u = up[t*3+0], v = up[t*3+1];
    int vid = (int)up[t*3+2];
    float xf = u*127.f, yf = v*127.f;
    int x0 = min(max((int)floorf(xf), 0), 126);
    int y0 = min(max((int)floorf(yf), 0), 126);
    float wx = xf - (float)x0, wy = yf - (float)y0;
    const short* cb = nts + ((size_t)((vid*128 + y0)*128 + x0))*64;
    #pragma unroll
    for (int kc=0;kc<2;kc++){
      const short* bp = cb + kc*32 + g*8;
      s8v c00 = *(const s8v*)(bp);
      s8v c01 = *(const s8v*)(bp + 64);
      s8v c10 = *(const s8v*)(bp + 8192);
      s8v c11 = *(const s8v*)(bp + 8192 + 64);
      float vals[8];
      #pragma unroll
      for (int e=0;e<8;e++){
        float a = b2f(c00[e]); a += wx*(b2f(c01[e]) - a);
        float b = b2f(c10[e]); b += wx*(b2f(c11[e]) - b);
        vals[e] = a + wy*(b - a);
      }
      float* op = outFeats + ((size_t)pt*3 + t)*64 + kc*32 + g*8;
      f4v v0 = {vals[0],vals[1],vals[2],vals[3]};
      f4v v1 = {vals[4],vals[5],vals[6],vals[7]};
      *(f4v*)op = v0;
      *(f4v*)(op+4) = v1;
      s8v pk;
      #pragma unroll
      for (int e=0;e<8;e++) pk[e] = f2bs(vals[e]);
      fb[t][kc] = pk;
    }
  }

  // ---- ray MLP hidden: relu(rw1 @ rd + rb1) in D-frag layout ----
  float rd0 = raydir[(size_t)pt*3+0];
  float rd1 = raydir[(size_t)pt*3+1];
  float rd2 = raydir[(size_t)pt*3+2];
  float h[4][4];
  #pragma unroll
  for (int m=0;m<4;m++){
    #pragma unroll
    for (int r=0;r<4;r++){
      int j = m*16 + g*4 + r;
      h[m][r] = fmaxf(rb1[j] + rw1[j*3]*rd0 + rw1[j*3+1]*rd1 + rw1[j*3+2]*rd2, 0.f);
    }
  }
  s8v xb[2];
  RELAYOUT(h, xb);

  // ---- rf = rw2 @ h + rb2 ----
  f4v acc[4];
  #pragma unroll
  for (int m=0;m<4;m++) acc[m] = FZ;
  #pragma unroll
  for (int kc=0;kc<2;kc++){
    #pragma unroll
    for (int m=0;m<4;m++)
      acc[m] = __builtin_amdgcn_mfma_f32_16x16x32_bf16(AFRG(rw2b), xb[kc], acc[m], 0,0,0);
  }
  float rf[4][4];
  #pragma unroll
  for (int m=0;m<4;m++){
    f4v bb = *(const f4v*)(rb2 + m*16 + g*4);
    #pragma unroll
    for (int r=0;r<4;r++) rf[m][r] = acc[m][r] + bb[r];
  }
  RELAYOUT(rf, xb);

  // ---- qh = wq @ rf + bq ----
  #pragma unroll
  for (int m=0;m<4;m++) acc[m] = FZ;
  #pragma unroll
  for (int kc=0;kc<2;kc++){
    #pragma unroll
    for (int m=0;m<4;m++)
      acc[m] = __builtin_amdgcn_mfma_f32_16x16x32_bf16(AFRG(wqb), xb[kc], acc[m], 0,0,0);
  }
  float qh[4][4];
  #pragma unroll
  for (int m=0;m<4;m++){
    f4v bb = *(const f4v*)(bq + m*16 + g*4);
    #pragma unroll
    for (int r=0;r<4;r++) qh[m][r] = acc[m][r] + bb[r];
  }

  // ---- K projections (wk frags preloaded, reused 3x) + scores ----
  s8v wkf[2][4];
  #pragma unroll
  for (int kc=0;kc<2;kc++)
    #pragma unroll
    for (int m=0;m<4;m++)
      wkf[kc][m] = AFRG(wkb);

  float sc[3][4];
  #pragma unroll
  for (int t=0;t<3;t++){
    f4v ka[4];
    #pragma unroll
    for (int m=0;m<4;m++) ka[m] = FZ;
    #pragma unroll
    for (int kc=0;kc<2;kc++){
      #pragma unroll
      for (int m=0;m<4;m++)
        ka[m] = __builtin_amdgcn_mfma_f32_16x16x32_bf16(wkf[kc][m], fb[t][kc], ka[m], 0,0,0);
    }
    #pragma unroll
    for (int m=0;m<4;m++){
      f4v bb = *(const f4v*)(bk + m*16 + g*4);
      float part = 0.f;
      #pragma unroll
      for (int r=0;r<4;r++) part += qh[m][r]*(ka[m][r] + bb[r]);
      part += __shfl_xor(part, 16, 64);
      part += __shfl_xor(part, 32, 64);
      sc[t][m] = part*0.25f;                  // / sqrt(16)
    }
  }

  // ---- softmax over 3 tokens (per head m) ----
  #pragma unroll
  for (int m=0;m<4;m++){
    float mx = fmaxf(fmaxf(sc[0][m], sc[1][m]), sc[2][m]);
    float e0 = __expf(sc[0][m]-mx);
    float e1 = __expf(sc[1][m]-mx);
    float e2 = __expf(sc[2][m]-mx);
    float inv = 1.f/(e0+e1+e2);
    sc[0][m] = e0*inv; sc[1][m] = e1*inv; sc[2][m] = e2*inv;
  }

  // ---- V projections scaled-accumulated per token (bv added once, sum(e)=1) ----
  s8v wvf[2][4];
  #pragma unroll
  for (int kc=0;kc<2;kc++)
    #pragma unroll
    for (int m=0;m<4;m++)
      wvf[kc][m] = AFRG(wvb);

  float o[4][4];
  #pragma unroll
  for (int m=0;m<4;m++)
    #pragma unroll
    for (int r=0;r<4;r++) o[m][r] = 0.f;
  #pragma unroll
  for (int t=0;t<3;t++){
    f4v va[4];
    #pragma unroll
    for (int m=0;m<4;m++) va[m] = FZ;
    #pragma unroll
    for (int kc=0;kc<2;kc++){
      #pragma unroll
      for (int m=0;m<4;m++)
        va[m] = __builtin_amdgcn_mfma_f32_16x16x32_bf16(wvf[kc][m], fb[t][kc], va[m], 0,0,0);
    }
    #pragma unroll
    for (int m=0;m<4;m++)
      #pragma unroll
      for (int r=0;r<4;r++) o[m][r] += sc[t][m]*va[m][r];
  }
  #pragma unroll
  for (int m=0;m<4;m++){
    f4v bb = *(const f4v*)(bv + m*16 + g*4);
    #pragma unroll
    for (int r=0;r<4;r++) o[m][r] += bb[r];
  }
  RELAYOUT(o, xb);

  // ---- out = wo @ o + bo ----
  #pragma unroll
  for (int m=0;m<4;m++) acc[m] = FZ;
  #pragma unroll
  for (int kc=0;kc<2;kc++){
    #pragma unroll
    for (int m=0;m<4;m++)
      acc[m] = __builtin_amdgcn_mfma_f32_16x16x32_bf16(AFRG(wob), xb[kc], acc[m], 0,0,0);
  }
  #pragma unroll
  for (int m=0;m<4;m++){
    f4v bb = *(const f4v*)(bo + m*16 + g*4);
    f4v res;
    #pragma unroll
    for (int r=0;r<4;r++) res[r] = acc[m][r] + bb[r];
    *(f4v*)(outFused + (size_t)pt*64 + m*16 + g*4) = res;
  }
#undef RELAYOUT
}

extern "C" void kernel_launch(void* const* d_in, const int* in_sizes, int n_in,
                              void* d_out, int out_size, void* d_ws, size_t ws_size,
                              hipStream_t stream)
{
  const float* view_tex = (const float*)d_in[0];
  const float* uvi    = (const float*)d_in[1];
  const float* raydir = (const float*)d_in[2];
  const float* w1 = (const float*)d_in[3];
  const float* b1 = (const float*)d_in[4];
  const float* w2 = (const float*)d_in[5];
  const float* b2 = (const float*)d_in[6];
  const float* w3 = (const float*)d_in[7];
  const float* b3 = (const float*)d_in[8];
  const float* rw1 = (const float*)d_in[9];
  const float* rb1 = (const float*)d_in[10];
  const float* rw2 = (const float*)d_in[11];
  const float* rb2 = (const float*)d_in[12];
  const float* wq = (const float*)d_in[13];
  const float* bq = (const float*)d_in[14];
  const float* wk = (const float*)d_in[15];
  const float* bk = (const float*)d_in[16];
  const float* wv = (const float*)d_in[17];
  const float* bv = (const float*)d_in[18];
  const float* wo = (const float*)d_in[19];
  const float* bo = (const float*)d_in[20];
  float* out = (float*)d_out;

  const int V = in_sizes[0] / (3*512*512);     // 8
  const int B = in_sizes[1] / 9;               // 262144
  const size_t FEATS_OFF = (size_t)B*64;

  const size_t C1F  = (size_t)V*512*512*32*2;
  const size_t C2F  = (size_t)V*256*256*64*2;
  const size_t C1V  = (size_t)512*512*32*2;
  const size_t C2V  = (size_t)256*256*64*2;
  const size_t NTSB = (size_t)V*128*128*64*2;
  const size_t WREG = 262144;

  char* base = (char*)d_ws;
  bool full = (ws_size >= C1F + C2F + NTSB + WREG);

  char *c1, *c2, *ntsp, *wreg;
  if (full){
    c1 = base; c2 = c1 + C1F; ntsp = c2 + C2F; wreg = ntsp + NTSB;
  } else {
    c1 = base; c2 = c1 + C1V; ntsp = c2 + C2V; wreg = ntsp + NTSB;
  }
  float* w1T = (float*)(wreg);
  short* w2b = (short*)(wreg + 3456);
  short* w3b = (short*)(wreg + 40320);
  short* rw2b = (short*)(wreg + 114048);
  short* wqb  = (short*)(wreg + 122240);
  short* wkb  = (short*)(wreg + 130432);
  short* wvb  = (short*)(wreg + 138624);
  short* wob  = (short*)(wreg + 146816);

  k0_prep<<<dim3(300),256,0,stream>>>(w1,w2,w3,rw2,wq,wk,wv,wo,wreg);

  if (full){
    k1_conv1<<<dim3(8,128,V),256,0,stream>>>(view_tex,(short*)c1,w1T,b1,0);
    conv_mfma<32><<<dim3(4,256,V),256,0,stream>>>((const short*)c1,(short*)c2,w2b,b2,512,512,256,0);
    conv_mfma<64><<<dim3(2,128,V),256,0,stream>>>((const short*)c2,(short*)ntsp,w3b,b3,256,256,128,0);
  } else {
    for (int v=0; v<V; v++){
      k1_conv1<<<dim3(8,128,1),256,0,stream>>>(view_tex,(short*)c1,w1T,b1,v);
      conv_mfma<32><<<dim3(4,256,1),256,0,stream>>>((const short*)c1,(short*)c2,w2b,b2,512,512,256,0);
      conv_mfma<64><<<dim3(2,128,1),256,0,stream>>>((const short*)c2,(short*)ntsp,w3b,b3,256,256,128,v);
    }
  }

  k5_fused<<<dim3(B/64),256,0,stream>>>((const short*)ntsp, uvi, raydir,
      rw1, rb1, rw2b, rb2, wqb, bq, wkb, bk, wvb, bv, wob, bo,
      out, out + FEATS_OFF);
}

// Round 3
// 398.668 us; speedup vs baseline: 1.2107x; 1.0699x over previous
//
#include <hip/hip_runtime.h>

typedef short s8v __attribute__((ext_vector_type(8)));
typedef short s4v __attribute__((ext_vector_type(4)));
typedef float f4v __attribute__((ext_vector_type(4)));

#define DEV __device__ __forceinline__

DEV short f2bs(float f){
  unsigned int u = __float_as_uint(f);
  u += 0x7fffu + ((u >> 16) & 1u);
  return (short)(u >> 16);
}
DEV float b2f(short s){
  return __uint_as_float(((unsigned int)(unsigned short)s) << 16);
}
DEV float lrelu(float x){ return x >= 0.f ? x : 0.01f*x; }

// ---------------- K0: weight prep ----------------
__global__ __launch_bounds__(256) void k0_prep(
    const float* __restrict__ w1, const float* __restrict__ w2,
    const float* __restrict__ w3, const float* __restrict__ rw2,
    const float* __restrict__ wq, const float* __restrict__ wk,
    const float* __restrict__ wv, const float* __restrict__ wo,
    char* __restrict__ wreg)
{
  int idx = blockIdx.x*256 + threadIdx.x;
  float* w1T = (float*)(wreg);
  short* w2b = (short*)(wreg + 3456);
  short* w3b = (short*)(wreg + 40320);
  short* rw2b = (short*)(wreg + 114048);
  short* wqb  = (short*)(wreg + 122240);
  short* wkb  = (short*)(wreg + 130432);
  short* wvb  = (short*)(wreg + 138624);
  short* wob  = (short*)(wreg + 146816);
  if (idx < 864){
    int k = idx >> 5, c = idx & 31;
    w1T[idx] = w1[c*27 + k];
  } else if (idx < 19296){
    int j = idx - 864;
    int kk = j / 2048, c = (j >> 5) & 63, ci = j & 31;
    w2b[j] = f2bs(w2[c*288 + ci*9 + kk]);
  } else if (idx < 56160){
    int j = idx - 19296;
    int kk = j / 4096, c = (j >> 6) & 63, ci = j & 63;
    w3b[j] = f2bs(w3[c*576 + ci*9 + kk]);
  } else if (idx < 60256){
    int j = idx - 56160; rw2b[j] = f2bs(rw2[j]);
  } else if (idx < 64352){
    int j = idx - 60256; wqb[j] = f2bs(wq[j]);
  } else if (idx < 68448){
    int j = idx - 64352; wkb[j] = f2bs(wk[j]);
  } else if (idx < 72544){
    int j = idx - 68448; wvb[j] = f2bs(wv[j]);
  } else if (idx < 76640){
    int j = idx - 72544; wob[j] = f2bs(wo[j]);
  }
}

// ---------------- K1: conv1 3->32, stride1, border pad (VALU fp32) ----------------
__global__ __launch_bounds__(256) void k1_conv1(
    const float* __restrict__ vt, short* __restrict__ dst,
    const float* __restrict__ w1T, const float* __restrict__ b1, int v0)
{
  int lane = threadIdx.x & 63, ty = threadIdx.x >> 6;
  int x = blockIdx.x*64 + lane;
  int y = blockIdx.y*4 + ty;
  const float* src = vt + (size_t)(v0 + blockIdx.z)*3*512*512;
  float xin[27];
  #pragma unroll
  for (int ci=0; ci<3; ci++){
    #pragma unroll
    for (int ky=0; ky<3; ky++){
      int iy = min(max(y+ky-1, 0), 511);
      #pragma unroll
      for (int kx=0; kx<3; kx++){
        int ix = min(max(x+kx-1, 0), 511);
        xin[(ci*3+ky)*3+kx] = src[(ci*512 + iy)*512 + ix];
      }
    }
  }
  float acc[32];
  #pragma unroll
  for (int c=0;c<32;c++) acc[c] = b1[c];
  #pragma unroll
  for (int k=0;k<27;k++){
    const float* wr = w1T + k*32;
    #pragma unroll
    for (int c=0;c<32;c++) acc[c] += wr[c]*xin[k];
  }
  s8v pk[4];
  #pragma unroll
  for (int c=0;c<32;c++) pk[c>>3][c&7] = f2bs(lrelu(acc[c]));
  short* o = dst + ((size_t)blockIdx.z*512*512 + (size_t)y*512 + x)*32;
  #pragma unroll
  for (int q=0;q<4;q++) *(s8v*)(o + q*8) = pk[q];
}

// ---------------- conv2/conv3: implicit-GEMM MFMA, stride 2, TILES px-tiles/wave ----------------
// wave covers TILES*16 output pixels in a row; A-frags (weights) reused across tiles.
template<int CIN, int TILES>
__global__ __launch_bounds__(256) void conv_mfma(
    const short* __restrict__ src0, short* __restrict__ dst,
    const short* __restrict__ wb, const float* __restrict__ bias,
    int IH, int IW, int OW, int dstV0)
{
  const int l = threadIdx.x & 63, w = threadIdx.x >> 6;
  const int p = l & 15, g = l >> 4;
  const int ox0 = blockIdx.x*(64*TILES) + w*(16*TILES) + p;
  const int oy = blockIdx.y;
  const short* src = src0 + (size_t)blockIdx.z*IH*IW*CIN;
  const f4v FZ = {0.f,0.f,0.f,0.f};
  f4v acc[TILES][4];
  #pragma unroll
  for (int tl=0;tl<TILES;tl++)
    #pragma unroll
    for (int m=0;m<4;m++) acc[tl][m] = FZ;
  #pragma unroll
  for (int ky=0;ky<3;ky++){
    int iy = min(max(2*oy+ky-1, 0), IH-1);
    #pragma unroll
    for (int kx=0;kx<3;kx++){
      #pragma unroll
      for (int ch=0; ch<CIN/32; ch++){
        s8v bfrag[TILES];
        #pragma unroll
        for (int tl=0;tl<TILES;tl++){
          int ix = min(max(2*(ox0 + 16*tl)+kx-1, 0), IW-1);
          bfrag[tl] = *(const s8v*)(src + ((size_t)iy*IW + ix)*CIN + ch*32 + g*8);
        }
        #pragma unroll
        for (int m=0;m<4;m++){
          s8v afrag = *(const s8v*)(wb + ((ky*3+kx)*64 + m*16 + p)*CIN + ch*32 + g*8);
          #pragma unroll
          for (int tl=0;tl<TILES;tl++)
            acc[tl][m] = __builtin_amdgcn_mfma_f32_16x16x32_bf16(afrag, bfrag[tl], acc[tl][m], 0,0,0);
        }
      }
    }
  }
  const int OH = gridDim.y;
  #pragma unroll
  for (int tl=0;tl<TILES;tl++){
    short* o = dst + (((size_t)(dstV0 + blockIdx.z)*OH + oy)*OW + ox0 + 16*tl)*64;
    #pragma unroll
    for (int m=0;m<4;m++){
      f4v bb = *(const f4v*)(bias + m*16 + g*4);
      s4v pk;
      #pragma unroll
      for (int r=0;r<4;r++) pk[r] = f2bs(lrelu(acc[tl][m][r] + bb[r]));
      *(s4v*)(o + m*16 + g*4) = pk;
    }
  }
}

// ---------------- K4: parallel bilinear gather ----------------
// thread = (token, 8-channel chunk). 4 independent 16B loads, interp, 32B store.
__global__ __launch_bounds__(256) void k4_gather(
    const short* __restrict__ nts, const float* __restrict__ uvi,
    float* __restrict__ outFeats)
{
  int gid = blockIdx.x*256 + threadIdx.x;
  int tk = gid >> 3, c = (gid & 7)*8;
  const float* up = uvi + (size_t)tk*3;
  float u = up[0], v = up[1];
  int vid = (int)up[2];
  float xf = u*127.f, yf = v*127.f;
  int x0 = min(max((int)floorf(xf), 0), 126);
  int y0 = min(max((int)floorf(yf), 0), 126);
  float wx = xf - (float)x0, wy = yf - (float)y0;
  const short* cb = nts + ((size_t)((vid*128 + y0)*128 + x0))*64 + c;
  s8v c00 = *(const s8v*)(cb);
  s8v c01 = *(const s8v*)(cb + 64);
  s8v c10 = *(const s8v*)(cb + 8192);
  s8v c11 = *(const s8v*)(cb + 8192 + 64);
  f4v o0, o1;
  #pragma unroll
  for (int e=0;e<8;e++){
    float a = b2f(c00[e]); a += wx*(b2f(c01[e]) - a);
    float b = b2f(c10[e]); b += wx*(b2f(c11[e]) - b);
    float val = a + wy*(b - a);
    if (e < 4) o0[e] = val; else o1[e-4] = val;
  }
  float* op = outFeats + (size_t)tk*64 + c;
  *(f4v*)op = o0;
  *(f4v*)(op+4) = o1;
}

// ---------------- K5: rayMLP + MHA (streaming; feats f32 from d_out) ----------------
#define AFRG(W) (*(const s8v*)((W) + (m*16 + p)*64 + kc*32 + g*8))

__global__ __launch_bounds__(256) void k5_attn(
    const float* __restrict__ feats, const float* __restrict__ raydir,
    const float* __restrict__ rw1, const float* __restrict__ rb1,
    const short* __restrict__ rw2b, const float* __restrict__ rb2,
    const short* __restrict__ wqb, const float* __restrict__ bq,
    const short* __restrict__ wkb, const float* __restrict__ bk,
    const short* __restrict__ wvb, const float* __restrict__ bv,
    const short* __restrict__ wob, const float* __restrict__ bo,
    float* __restrict__ outFused)
{
  __shared__ uint4 ldsq[576];                 // 4 waves * 16 pts * 72 bf16 (pad 64->72)
  unsigned int* ldsu = (unsigned int*)ldsq;
  const int l = threadIdx.x & 63, wid = threadIdx.x >> 6;
  const int p = l & 15, g = l >> 4;
  const int pt = blockIdx.x*64 + wid*16 + p;
  const f4v FZ = {0.f,0.f,0.f,0.f};

#define RELAYOUT(H, OB) { \
    _Pragma("unroll") \
    for (int m_=0;m_<4;m_++){ \
      unsigned int lo_ = (unsigned int)(unsigned short)f2bs(H[m_][0]) \
                       | ((unsigned int)(unsigned short)f2bs(H[m_][1])<<16); \
      unsigned int hi_ = (unsigned int)(unsigned short)f2bs(H[m_][2]) \
                       | ((unsigned int)(unsigned short)f2bs(H[m_][3])<<16); \
      int di_ = wid*576 + p*36 + m_*8 + g*2; \
      ldsu[di_] = lo_; ldsu[di_+1] = hi_; \
    } \
    OB[0] = __builtin_bit_cast(s8v, ldsq[wid*144 + p*9 + g]); \
    OB[1] = __builtin_bit_cast(s8v, ldsq[wid*144 + p*9 + 4 + g]); \
  }

  // ---- load feats (f32, coalesced streaming) -> bf16 B-frags ----
  s8v fb[3][2];
  #pragma unroll
  for (int t=0;t<3;t++){
    const float* fp = feats + (size_t)(pt*3+t)*64;
    #pragma unroll
    for (int kc=0;kc<2;kc++){
      f4v a0 = *(const f4v*)(fp + kc*32 + g*8);
      f4v a1 = *(const f4v*)(fp + kc*32 + g*8 + 4);
      s8v tmp;
      #pragma unroll
      for (int e=0;e<4;e++){ tmp[e] = f2bs(a0[e]); tmp[e+4] = f2bs(a1[e]); }
      fb[t][kc] = tmp;
    }
  }

  // ---- ray MLP hidden: relu(rw1 @ rd + rb1) in D-frag layout ----
  float rd0 = raydir[(size_t)pt*3+0];
  float rd1 = raydir[(size_t)pt*3+1];
  float rd2 = raydir[(size_t)pt*3+2];
  float h[4][4];
  #pragma unroll
  for (int m=0;m<4;m++){
    #pragma unroll
    for (int r=0;r<4;r++){
      int j = m*16 + g*4 + r;
      h[m][r] = fmaxf(rb1[j] + rw1[j*3]*rd0 + rw1[j*3+1]*rd1 + rw1[j*3+2]*rd2, 0.f);
    }
  }
  s8v xb[2];
  RELAYOUT(h, xb);

  // ---- rf = rw2 @ h + rb2 ----
  f4v acc[4];
  #pragma unroll
  for (int m=0;m<4;m++) acc[m] = FZ;
  #pragma unroll
  for (int kc=0;kc<2;kc++){
    #pragma unroll
    for (int m=0;m<4;m++)
      acc[m] = __builtin_amdgcn_mfma_f32_16x16x32_bf16(AFRG(rw2b), xb[kc], acc[m], 0,0,0);
  }
  float rf[4][4];
  #pragma unroll
  for (int m=0;m<4;m++){
    f4v bb = *(const f4v*)(rb2 + m*16 + g*4);
    #pragma unroll
    for (int r=0;r<4;r++) rf[m][r] = acc[m][r] + bb[r];
  }
  RELAYOUT(rf, xb);

  // ---- qh = wq @ rf + bq ----
  #pragma unroll
  for (int m=0;m<4;m++) acc[m] = FZ;
  #pragma unroll
  for (int kc=0;kc<2;kc++){
    #pragma unroll
    for (int m=0;m<4;m++)
      acc[m] = __builtin_amdgcn_mfma_f32_16x16x32_bf16(AFRG(wqb), xb[kc], acc[m], 0,0,0);
  }
  float qh[4][4];
  #pragma unroll
  for (int m=0;m<4;m++){
    f4v bb = *(const f4v*)(bq + m*16 + g*4);
    #pragma unroll
    for (int r=0;r<4;r++) qh[m][r] = acc[m][r] + bb[r];
  }

  // ---- K projections (wk frags preloaded, reused 3x) + scores ----
  s8v wkf[2][4];
  #pragma unroll
  for (int kc=0;kc<2;kc++)
    #pragma unroll
    for (int m=0;m<4;m++)
      wkf[kc][m] = AFRG(wkb);

  float sc[3][4];
  #pragma unroll
  for (int t=0;t<3;t++){
    f4v ka[4];
    #pragma unroll
    for (int m=0;m<4;m++) ka[m] = FZ;
    #pragma unroll
    for (int kc=0;kc<2;kc++){
      #pragma unroll
      for (int m=0;m<4;m++)
        ka[m] = __builtin_amdgcn_mfma_f32_16x16x32_bf16(wkf[kc][m], fb[t][kc], ka[m], 0,0,0);
    }
    #pragma unroll
    for (int m=0;m<4;m++){
      f4v bb = *(const f4v*)(bk + m*16 + g*4);
      float part = 0.f;
      #pragma unroll
      for (int r=0;r<4;r++) part += qh[m][r]*(ka[m][r] + bb[r]);
      part += __shfl_xor(part, 16, 64);
      part += __shfl_xor(part, 32, 64);
      sc[t][m] = part*0.25f;                  // / sqrt(16)
    }
  }

  // ---- softmax over 3 tokens (per head m) ----
  #pragma unroll
  for (int m=0;m<4;m++){
    float mx = fmaxf(fmaxf(sc[0][m], sc[1][m]), sc[2][m]);
    float e0 = __expf(sc[0][m]-mx);
    float e1 = __expf(sc[1][m]-mx);
    float e2 = __expf(sc[2][m]-mx);
    float inv = 1.f/(e0+e1+e2);
    sc[0][m] = e0*inv; sc[1][m] = e1*inv; sc[2][m] = e2*inv;
  }

  // ---- V projections scaled-accumulated per token (bv added once, sum(e)=1) ----
  s8v wvf[2][4];
  #pragma unroll
  for (int kc=0;kc<2;kc++)
    #pragma unroll
    for (int m=0;m<4;m++)
      wvf[kc][m] = AFRG(wvb);

  float o[4][4];
  #pragma unroll
  for (int m=0;m<4;m++)
    #pragma unroll
    for (int r=0;r<4;r++) o[m][r] = 0.f;
  #pragma unroll
  for (int t=0;t<3;t++){
    f4v va[4];
    #pragma unroll
    for (int m=0;m<4;m++) va[m] = FZ;
    #pragma unroll
    for (int kc=0;kc<2;kc++){
      #pragma unroll
      for (int m=0;m<4;m++)
        va[m] = __builtin_amdgcn_mfma_f32_16x16x32_bf16(wvf[kc][m], fb[t][kc], va[m], 0,0,0);
    }
    #pragma unroll
    for (int m=0;m<4;m++)
      #pragma unroll
      for (int r=0;r<4;r++) o[m][r] += sc[t][m]*va[m][r];
  }
  #pragma unroll
  for (int m=0;m<4;m++){
    f4v bb = *(const f4v*)(bv + m*16 + g*4);
    #pragma unroll
    for (int r=0;r<4;r++) o[m][r] += bb[r];
  }
  RELAYOUT(o, xb);

  // ---- out = wo @ o + bo ----
  #pragma unroll
  for (int m=0;m<4;m++) acc[m] = FZ;
  #pragma unroll
  for (int kc=0;kc<2;kc++){
    #pragma unroll
    for (int m=0;m<4;m++)
      acc[m] = __builtin_amdgcn_mfma_f32_16x16x32_bf16(AFRG(wob), xb[kc], acc[m], 0,0,0);
  }
  #pragma unroll
  for (int m=0;m<4;m++){
    f4v bb = *(const f4v*)(bo + m*16 + g*4);
    f4v res;
    #pragma unroll
    for (int r=0;r<4;r++) res[r] = acc[m][r] + bb[r];
    *(f4v*)(outFused + (size_t)pt*64 + m*16 + g*4) = res;
  }
#undef RELAYOUT
}

extern "C" void kernel_launch(void* const* d_in, const int* in_sizes, int n_in,
                              void* d_out, int out_size, void* d_ws, size_t ws_size,
                              hipStream_t stream)
{
  const float* view_tex = (const float*)d_in[0];
  const float* uvi    = (const float*)d_in[1];
  const float* raydir = (const float*)d_in[2];
  const float* w1 = (const float*)d_in[3];
  const float* b1 = (const float*)d_in[4];
  const float* w2 = (const float*)d_in[5];
  const float* b2 = (const float*)d_in[6];
  const float* w3 = (const float*)d_in[7];
  const float* b3 = (const float*)d_in[8];
  const float* rw1 = (const float*)d_in[9];
  const float* rb1 = (const float*)d_in[10];
  const float* rw2 = (const float*)d_in[11];
  const float* rb2 = (const float*)d_in[12];
  const float* wq = (const float*)d_in[13];
  const float* bq = (const float*)d_in[14];
  const float* wk = (const float*)d_in[15];
  const float* bk = (const float*)d_in[16];
  const float* wv = (const float*)d_in[17];
  const float* bv = (const float*)d_in[18];
  const float* wo = (const float*)d_in[19];
  const float* bo = (const float*)d_in[20];
  float* out = (float*)d_out;

  const int V = in_sizes[0] / (3*512*512);     // 8
  const int B = in_sizes[1] / 9;               // 262144
  const size_t FEATS_OFF = (size_t)B*64;

  const size_t C1F  = (size_t)V*512*512*32*2;
  const size_t C2F  = (size_t)V*256*256*64*2;
  const size_t C1V  = (size_t)512*512*32*2;
  const size_t C2V  = (size_t)256*256*64*2;
  const size_t NTSB = (size_t)V*128*128*64*2;
  const size_t WREG = 262144;

  char* base = (char*)d_ws;
  bool full = (ws_size >= C1F + C2F + NTSB + WREG);

  char *c1, *c2, *ntsp, *wreg;
  if (full){
    c1 = base; c2 = c1 + C1F; ntsp = c2 + C2F; wreg = ntsp + NTSB;
  } else {
    c1 = base; c2 = c1 + C1V; ntsp = c2 + C2V; wreg = ntsp + NTSB;
  }
  float* w1T = (float*)(wreg);
  short* w2b = (short*)(wreg + 3456);
  short* w3b = (short*)(wreg + 40320);
  short* rw2b = (short*)(wreg + 114048);
  short* wqb  = (short*)(wreg + 122240);
  short* wkb  = (short*)(wreg + 130432);
  short* wvb  = (short*)(wreg + 138624);
  short* wob  = (short*)(wreg + 146816);

  k0_prep<<<dim3(300),256,0,stream>>>(w1,w2,w3,rw2,wq,wk,wv,wo,wreg);

  if (full){
    k1_conv1<<<dim3(8,128,V),256,0,stream>>>(view_tex,(short*)c1,w1T,b1,0);
    conv_mfma<32,2><<<dim3(2,256,V),256,0,stream>>>((const short*)c1,(short*)c2,w2b,b2,512,512,256,0);
    conv_mfma<64,2><<<dim3(1,128,V),256,0,stream>>>((const short*)c2,(short*)ntsp,w3b,b3,256,256,128,0);
  } else {
    for (int v=0; v<V; v++){
      k1_conv1<<<dim3(8,128,1),256,0,stream>>>(view_tex,(short*)c1,w1T,b1,v);
      conv_mfma<32,2><<<dim3(2,256,1),256,0,stream>>>((const short*)c1,(short*)c2,w2b,b2,512,512,256,0);
      conv_mfma<64,2><<<dim3(1,128,1),256,0,stream>>>((const short*)c2,(short*)ntsp,w3b,b3,256,256,128,v);
    }
  }

  k4_gather<<<dim3((B*3*8)/256),256,0,stream>>>((const short*)ntsp, uvi, out + FEATS_OFF);

  k5_attn<<<dim3(B/64),256,0,stream>>>(out + FEATS_OFF, raydir,
      rw1, rb1, rw2b, rb2, wqb, bq, wkb, bk, wvb, bv, wob, bo, out);
}

// Round 4
// 397.277 us; speedup vs baseline: 1.2149x; 1.0035x over previous
//
#include <hip/hip_runtime.h>

typedef short s8v __attribute__((ext_vector_type(8)));
typedef short s4v __attribute__((ext_vector_type(4)));
typedef float f4v __attribute__((ext_vector_type(4)));

#define DEV __device__ __forceinline__

DEV short f2bs(float f){
  unsigned int u = __float_as_uint(f);
  u += 0x7fffu + ((u >> 16) & 1u);
  return (short)(u >> 16);
}
DEV float b2f(short s){
  return __uint_as_float(((unsigned int)(unsigned short)s) << 16);
}
DEV float lrelu(float x){ return x >= 0.f ? x : 0.01f*x; }

// ---------------- K0: weight prep ----------------
__global__ __launch_bounds__(256) void k0_prep(
    const float* __restrict__ w1, const float* __restrict__ w2,
    const float* __restrict__ w3, const float* __restrict__ rw2,
    const float* __restrict__ wq, const float* __restrict__ wk,
    const float* __restrict__ wv, const float* __restrict__ wo,
    char* __restrict__ wreg)
{
  int idx = blockIdx.x*256 + threadIdx.x;
  float* w1T = (float*)(wreg);
  short* w2b = (short*)(wreg + 3456);
  short* w3b = (short*)(wreg + 40320);
  short* rw2b = (short*)(wreg + 114048);
  short* wqb  = (short*)(wreg + 122240);
  short* wkb  = (short*)(wreg + 130432);
  short* wvb  = (short*)(wreg + 138624);
  short* wob  = (short*)(wreg + 146816);
  if (idx < 864){
    int k = idx >> 5, c = idx & 31;
    w1T[idx] = w1[c*27 + k];
  } else if (idx < 19296){
    int j = idx - 864;
    int kk = j / 2048, c = (j >> 5) & 63, ci = j & 31;
    w2b[j] = f2bs(w2[c*288 + ci*9 + kk]);
  } else if (idx < 56160){
    int j = idx - 19296;
    int kk = j / 4096, c = (j >> 6) & 63, ci = j & 63;
    w3b[j] = f2bs(w3[c*576 + ci*9 + kk]);
  } else if (idx < 60256){
    int j = idx - 56160; rw2b[j] = f2bs(rw2[j]);
  } else if (idx < 64352){
    int j = idx - 60256; wqb[j] = f2bs(wq[j]);
  } else if (idx < 68448){
    int j = idx - 64352; wkb[j] = f2bs(wk[j]);
  } else if (idx < 72544){
    int j = idx - 68448; wvb[j] = f2bs(wv[j]);
  } else if (idx < 76640){
    int j = idx - 72544; wob[j] = f2bs(wo[j]);
  }
}

// ---------------- K1: conv1 3->32, stride1, border pad (VALU fp32) ----------------
__global__ __launch_bounds__(256) void k1_conv1(
    const float* __restrict__ vt, short* __restrict__ dst,
    const float* __restrict__ w1T, const float* __restrict__ b1, int v0)
{
  int lane = threadIdx.x & 63, ty = threadIdx.x >> 6;
  int x = blockIdx.x*64 + lane;
  int y = blockIdx.y*4 + ty;
  const float* src = vt + (size_t)(v0 + blockIdx.z)*3*512*512;
  float xin[27];
  #pragma unroll
  for (int ci=0; ci<3; ci++){
    #pragma unroll
    for (int ky=0; ky<3; ky++){
      int iy = min(max(y+ky-1, 0), 511);
      #pragma unroll
      for (int kx=0; kx<3; kx++){
        int ix = min(max(x+kx-1, 0), 511);
        xin[(ci*3+ky)*3+kx] = src[(ci*512 + iy)*512 + ix];
      }
    }
  }
  float acc[32];
  #pragma unroll
  for (int c=0;c<32;c++) acc[c] = b1[c];
  #pragma unroll
  for (int k=0;k<27;k++){
    const float* wr = w1T + k*32;
    #pragma unroll
    for (int c=0;c<32;c++) acc[c] += wr[c]*xin[k];
  }
  s8v pk[4];
  #pragma unroll
  for (int c=0;c<32;c++) pk[c>>3][c&7] = f2bs(lrelu(acc[c]));
  short* o = dst + ((size_t)blockIdx.z*512*512 + (size_t)y*512 + x)*32;
  #pragma unroll
  for (int q=0;q<4;q++) *(s8v*)(o + q*8) = pk[q];
}

// ---------------- conv2/conv3: implicit-GEMM MFMA, stride 2, TILES px-tiles/wave ----------------
// wave covers TILES*16 output pixels in a row; A-frags (weights) reused across tiles.
template<int CIN, int TILES>
__global__ __launch_bounds__(256) void conv_mfma(
    const short* __restrict__ src0, short* __restrict__ dst,
    const short* __restrict__ wb, const float* __restrict__ bias,
    int IH, int IW, int OW, int dstV0)
{
  const int l = threadIdx.x & 63, w = threadIdx.x >> 6;
  const int p = l & 15, g = l >> 4;
  const int ox0 = blockIdx.x*(64*TILES) + w*(16*TILES) + p;
  const int oy = blockIdx.y;
  const short* src = src0 + (size_t)blockIdx.z*IH*IW*CIN;
  const f4v FZ = {0.f,0.f,0.f,0.f};
  f4v acc[TILES][4];
  #pragma unroll
  for (int tl=0;tl<TILES;tl++)
    #pragma unroll
    for (int m=0;m<4;m++) acc[tl][m] = FZ;
  #pragma unroll
  for (int ky=0;ky<3;ky++){
    int iy = min(max(2*oy+ky-1, 0), IH-1);
    #pragma unroll
    for (int kx=0;kx<3;kx++){
      #pragma unroll
      for (int ch=0; ch<CIN/32; ch++){
        s8v bfrag[TILES];
        #pragma unroll
        for (int tl=0;tl<TILES;tl++){
          int ix = min(max(2*(ox0 + 16*tl)+kx-1, 0), IW-1);
          bfrag[tl] = *(const s8v*)(src + ((size_t)iy*IW + ix)*CIN + ch*32 + g*8);
        }
        #pragma unroll
        for (int m=0;m<4;m++){
          s8v afrag = *(const s8v*)(wb + ((ky*3+kx)*64 + m*16 + p)*CIN + ch*32 + g*8);
          #pragma unroll
          for (int tl=0;tl<TILES;tl++)
            acc[tl][m] = __builtin_amdgcn_mfma_f32_16x16x32_bf16(afrag, bfrag[tl], acc[tl][m], 0,0,0);
        }
      }
    }
  }
  const int OH = gridDim.y;
  #pragma unroll
  for (int tl=0;tl<TILES;tl++){
    short* o = dst + (((size_t)(dstV0 + blockIdx.z)*OH + oy)*OW + ox0 + 16*tl)*64;
    #pragma unroll
    for (int m=0;m<4;m++){
      f4v bb = *(const f4v*)(bias + m*16 + g*4);
      s4v pk;
      #pragma unroll
      for (int r=0;r<4;r++) pk[r] = f2bs(lrelu(acc[tl][m][r] + bb[r]));
      *(s4v*)(o + m*16 + g*4) = pk;
    }
  }
}

// ---------------- K4: parallel bilinear gather ----------------
// thread = (token, 8-channel chunk). 4 independent 16B loads, interp, 32B store.
__global__ __launch_bounds__(256) void k4_gather(
    const short* __restrict__ nts, const float* __restrict__ uvi,
    float* __restrict__ outFeats)
{
  int gid = blockIdx.x*256 + threadIdx.x;
  int tk = gid >> 3, c = (gid & 7)*8;
  const float* up = uvi + (size_t)tk*3;
  float u = up[0], v = up[1];
  int vid = (int)up[2];
  float xf = u*127.f, yf = v*127.f;
  int x0 = min(max((int)floorf(xf), 0), 126);
  int y0 = min(max((int)floorf(yf), 0), 126);
  float wx = xf - (float)x0, wy = yf - (float)y0;
  const short* cb = nts + ((size_t)((vid*128 + y0)*128 + x0))*64 + c;
  s8v c00 = *(const s8v*)(cb);
  s8v c01 = *(const s8v*)(cb + 64);
  s8v c10 = *(const s8v*)(cb + 8192);
  s8v c11 = *(const s8v*)(cb + 8192 + 64);
  f4v o0, o1;
  #pragma unroll
  for (int e=0;e<8;e++){
    float a = b2f(c00[e]); a += wx*(b2f(c01[e]) - a);
    float b = b2f(c10[e]); b += wx*(b2f(c11[e]) - b);
    float val = a + wy*(b - a);
    if (e < 4) o0[e] = val; else o1[e-4] = val;
  }
  float* op = outFeats + (size_t)tk*64 + c;
  *(f4v*)op = o0;
  *(f4v*)(op+4) = o1;
}

// ---------------- K5: rayMLP + MHA (streaming; feats f32 from d_out) ----------------
// lane: p = l&15 (point), g = l>>4. B-frag: col=p, k=kc*32+g*8+e. D-frag: row=m*16+g*4+r, col=p.
#define AFRG(W) (*(const s8v*)((W) + (m*16 + p)*64 + kc*32 + g*8))

__global__ __launch_bounds__(256) void k5_attn(
    const float* __restrict__ feats, const float* __restrict__ raydir,
    const float* __restrict__ rw1, const float* __restrict__ rb1,
    const short* __restrict__ rw2b, const float* __restrict__ rb2,
    const short* __restrict__ wqb, const float* __restrict__ bq,
    const short* __restrict__ wkb, const float* __restrict__ bk,
    const short* __restrict__ wvb, const float* __restrict__ bv,
    const short* __restrict__ wob, const float* __restrict__ bo,
    float* __restrict__ outFused)
{
  __shared__ uint4 ldsq[576];                 // 4 waves * 16 pts * 72 bf16 (pad 64->72)
  unsigned int* ldsu = (unsigned int*)ldsq;
  const int l = threadIdx.x & 63, wid = threadIdx.x >> 6;
  const int p = l & 15, g = l >> 4;
  const int pt = blockIdx.x*64 + wid*16 + p;
  const f4v FZ = {0.f,0.f,0.f,0.f};

#define RELAYOUT(H, OB) { \
    _Pragma("unroll") \
    for (int m_=0;m_<4;m_++){ \
      unsigned int lo_ = (unsigned int)(unsigned short)f2bs(H[m_][0]) \
                       | ((unsigned int)(unsigned short)f2bs(H[m_][1])<<16); \
      unsigned int hi_ = (unsigned int)(unsigned short)f2bs(H[m_][2]) \
                       | ((unsigned int)(unsigned short)f2bs(H[m_][3])<<16); \
      int di_ = wid*576 + p*36 + m_*8 + g*2; \
      ldsu[di_] = lo_; ldsu[di_+1] = hi_; \
    } \
    OB[0] = __builtin_bit_cast(s8v, ldsq[wid*144 + p*9 + g]); \
    OB[1] = __builtin_bit_cast(s8v, ldsq[wid*144 + p*9 + 4 + g]); \
  }

  // ---- load feats (f32, coalesced streaming) -> bf16 B-frags ----
  s8v fb[3][2];
  #pragma unroll
  for (int t=0;t<3;t++){
    const float* fp = feats + (size_t)(pt*3+t)*64;
    #pragma unroll
    for (int kc=0;kc<2;kc++){
      f4v a0 = *(const f4v*)(fp + kc*32 + g*8);
      f4v a1 = *(const f4v*)(fp + kc*32 + g*8 + 4);
      s8v tmp;
      #pragma unroll
      for (int e=0;e<4;e++){ tmp[e] = f2bs(a0[e]); tmp[e+4] = f2bs(a1[e]); }
      fb[t][kc] = tmp;
    }
  }

  // ---- ray MLP hidden directly in B-frag layout: lane (p,g) owns k = kc*32+g*8+e ----
  float rd0 = raydir[(size_t)pt*3+0];
  float rd1 = raydir[(size_t)pt*3+1];
  float rd2 = raydir[(size_t)pt*3+2];
  s8v xb[2];
  #pragma unroll
  for (int kc=0;kc<2;kc++){
    s8v tmp;
    #pragma unroll
    for (int e=0;e<8;e++){
      int j = kc*32 + g*8 + e;
      float hv = fmaxf(rb1[j] + rw1[j*3]*rd0 + rw1[j*3+1]*rd1 + rw1[j*3+2]*rd2, 0.f);
      tmp[e] = f2bs(hv);
    }
    xb[kc] = tmp;
  }

  // ---- rf = rw2 @ h + rb2 ----
  f4v acc[4];
  #pragma unroll
  for (int m=0;m<4;m++) acc[m] = FZ;
  #pragma unroll
  for (int kc=0;kc<2;kc++){
    #pragma unroll
    for (int m=0;m<4;m++)
      acc[m] = __builtin_amdgcn_mfma_f32_16x16x32_bf16(AFRG(rw2b), xb[kc], acc[m], 0,0,0);
  }
  float rf[4][4];
  #pragma unroll
  for (int m=0;m<4;m++){
    f4v bb = *(const f4v*)(rb2 + m*16 + g*4);
    #pragma unroll
    for (int r=0;r<4;r++) rf[m][r] = acc[m][r] + bb[r];
  }
  RELAYOUT(rf, xb);

  // ---- qh = wq @ rf + bq (kept in D-frag; only used for per-lane dots) ----
  #pragma unroll
  for (int m=0;m<4;m++) acc[m] = FZ;
  #pragma unroll
  for (int kc=0;kc<2;kc++){
    #pragma unroll
    for (int m=0;m<4;m++)
      acc[m] = __builtin_amdgcn_mfma_f32_16x16x32_bf16(AFRG(wqb), xb[kc], acc[m], 0,0,0);
  }
  float qh[4][4];
  #pragma unroll
  for (int m=0;m<4;m++){
    f4v bb = *(const f4v*)(bq + m*16 + g*4);
    #pragma unroll
    for (int r=0;r<4;r++) qh[m][r] = acc[m][r] + bb[r];
  }

  // ---- K projections (wk frags preloaded, reused 3x) + scores ----
  s8v wkf[2][4];
  #pragma unroll
  for (int kc=0;kc<2;kc++)
    #pragma unroll
    for (int m=0;m<4;m++)
      wkf[kc][m] = AFRG(wkb);

  float sc[3][4];
  #pragma unroll
  for (int t=0;t<3;t++){
    f4v ka[4];
    #pragma unroll
    for (int m=0;m<4;m++) ka[m] = FZ;
    #pragma unroll
    for (int kc=0;kc<2;kc++){
      #pragma unroll
      for (int m=0;m<4;m++)
        ka[m] = __builtin_amdgcn_mfma_f32_16x16x32_bf16(wkf[kc][m], fb[t][kc], ka[m], 0,0,0);
    }
    #pragma unroll
    for (int m=0;m<4;m++){
      f4v bb = *(const f4v*)(bk + m*16 + g*4);
      float part = 0.f;
      #pragma unroll
      for (int r=0;r<4;r++) part += qh[m][r]*(ka[m][r] + bb[r]);
      part += __shfl_xor(part, 16, 64);
      part += __shfl_xor(part, 32, 64);
      sc[t][m] = part*0.25f;                  // / sqrt(16)
    }
  }

  // ---- softmax over 3 tokens (per head m) ----
  #pragma unroll
  for (int m=0;m<4;m++){
    float mx = fmaxf(fmaxf(sc[0][m], sc[1][m]), sc[2][m]);
    float e0 = __expf(sc[0][m]-mx);
    float e1 = __expf(sc[1][m]-mx);
    float e2 = __expf(sc[2][m]-mx);
    float inv = 1.f/(e0+e1+e2);
    sc[0][m] = e0*inv; sc[1][m] = e1*inv; sc[2][m] = e2*inv;
  }

  // ---- V projections scaled-accumulated per token (bv added once, sum(e)=1) ----
  s8v wvf[2][4];
  #pragma unroll
  for (int kc=0;kc<2;kc++)
    #pragma unroll
    for (int m=0;m<4;m++)
      wvf[kc][m] = AFRG(wvb);

  float o[4][4];
  #pragma unroll
  for (int m=0;m<4;m++)
    #pragma unroll
    for (int r=0;r<4;r++) o[m][r] = 0.f;
  #pragma unroll
  for (int t=0;t<3;t++){
    f4v va[4];
    #pragma unroll
    for (int m=0;m<4;m++) va[m] = FZ;
    #pragma unroll
    for (int kc=0;kc<2;kc++){
      #pragma unroll
      for (int m=0;m<4;m++)
        va[m] = __builtin_amdgcn_mfma_f32_16x16x32_bf16(wvf[kc][m], fb[t][kc], va[m], 0,0,0);
    }
    #pragma unroll
    for (int m=0;m<4;m++)
      #pragma unroll
      for (int r=0;r<4;r++) o[m][r] += sc[t][m]*va[m][r];
  }
  #pragma unroll
  for (int m=0;m<4;m++){
    f4v bb = *(const f4v*)(bv + m*16 + g*4);
    #pragma unroll
    for (int r=0;r<4;r++) o[m][r] += bb[r];
  }
  RELAYOUT(o, xb);

  // ---- out = wo @ o + bo ----
  #pragma unroll
  for (int m=0;m<4;m++) acc[m] = FZ;
  #pragma unroll
  for (int kc=0;kc<2;kc++){
    #pragma unroll
    for (int m=0;m<4;m++)
      acc[m] = __builtin_amdgcn_mfma_f32_16x16x32_bf16(AFRG(wob), xb[kc], acc[m], 0,0,0);
  }
  #pragma unroll
  for (int m=0;m<4;m++){
    f4v bb = *(const f4v*)(bo + m*16 + g*4);
    f4v res;
    #pragma unroll
    for (int r=0;r<4;r++) res[r] = acc[m][r] + bb[r];
    *(f4v*)(outFused + (size_t)pt*64 + m*16 + g*4) = res;
  }
#undef RELAYOUT
}

extern "C" void kernel_launch(void* const* d_in, const int* in_sizes, int n_in,
                              void* d_out, int out_size, void* d_ws, size_t ws_size,
                              hipStream_t stream)
{
  const float* view_tex = (const float*)d_in[0];
  const float* uvi    = (const float*)d_in[1];
  const float* raydir = (const float*)d_in[2];
  const float* w1 = (const float*)d_in[3];
  const float* b1 = (const float*)d_in[4];
  const float* w2 = (const float*)d_in[5];
  const float* b2 = (const float*)d_in[6];
  const float* w3 = (const float*)d_in[7];
  const float* b3 = (const float*)d_in[8];
  const float* rw1 = (const float*)d_in[9];
  const float* rb1 = (const float*)d_in[10];
  const float* rw2 = (const float*)d_in[11];
  const float* rb2 = (const float*)d_in[12];
  const float* wq = (const float*)d_in[13];
  const float* bq = (const float*)d_in[14];
  const float* wk = (const float*)d_in[15];
  const float* bk = (const float*)d_in[16];
  const float* wv = (const float*)d_in[17];
  const float* bv = (const float*)d_in[18];
  const float* wo = (const float*)d_in[19];
  const float* bo = (const float*)d_in[20];
  float* out = (float*)d_out;

  const int V = in_sizes[0] / (3*512*512);     // 8
  const int B = in_sizes[1] / 9;               // 262144
  const size_t FEATS_OFF = (size_t)B*64;

  const size_t C1F  = (size_t)V*512*512*32*2;
  const size_t C2F  = (size_t)V*256*256*64*2;
  const size_t C1V  = (size_t)512*512*32*2;
  const size_t C2V  = (size_t)256*256*64*2;
  const size_t NTSB = (size_t)V*128*128*64*2;
  const size_t WREG = 262144;

  char* base = (char*)d_ws;
  bool full = (ws_size >= C1F + C2F + NTSB + WREG);

  char *c1, *c2, *ntsp, *wreg;
  if (full){
    c1 = base; c2 = c1 + C1F; ntsp = c2 + C2F; wreg = ntsp + NTSB;
  } else {
    c1 = base; c2 = c1 + C1V; ntsp = c2 + C2V; wreg = ntsp + NTSB;
  }
  float* w1T = (float*)(wreg);
  short* w2b = (short*)(wreg + 3456);
  short* w3b = (short*)(wreg + 40320);
  short* rw2b = (short*)(wreg + 114048);
  short* wqb  = (short*)(wreg + 122240);
  short* wkb  = (short*)(wreg + 130432);
  short* wvb  = (short*)(wreg + 138624);
  short* wob  = (short*)(wreg + 146816);

  k0_prep<<<dim3(300),256,0,stream>>>(w1,w2,w3,rw2,wq,wk,wv,wo,wreg);

  if (full){
    k1_conv1<<<dim3(8,128,V),256,0,stream>>>(view_tex,(short*)c1,w1T,b1,0);
    conv_mfma<32,4><<<dim3(1,256,V),256,0,stream>>>((const short*)c1,(short*)c2,w2b,b2,512,512,256,0);
    conv_mfma<64,2><<<dim3(1,128,V),256,0,stream>>>((const short*)c2,(short*)ntsp,w3b,b3,256,256,128,0);
  } else {
    for (int v=0; v<V; v++){
      k1_conv1<<<dim3(8,128,1),256,0,stream>>>(view_tex,(short*)c1,w1T,b1,v);
      conv_mfma<32,4><<<dim3(1,256,1),256,0,stream>>>((const short*)c1,(short*)c2,w2b,b2,512,512,256,0);
      conv_mfma<64,2><<<dim3(1,128,1),256,0,stream>>>((const short*)c2,(short*)ntsp,w3b,b3,256,256,128,v);
    }
  }

  k4_gather<<<dim3((B*3*8)/256),256,0,stream>>>((const short*)ntsp, uvi, out + FEATS_OFF);

  k5_attn<<<dim3(B/64),256,0,stream>>>(out + FEATS_OFF, raydir,
      rw1, rb1, rw2b, rb2, wqb, bq, wkb, bk, wvb, bv, wob, bo, out);
}